// Round 1
// baseline (133.726 us; speedup 1.0000x reference)
//
#include <hip/hip_runtime.h>

namespace {

constexpr int B = 16, C = 3, H = 512, W = 1024;
constexpr int HW = H * W;                 // 2^19
constexpr int NPIX = B * HW;              // 8388608
constexpr int BLOCK = 256;
constexpr int GRID = 2048;                // 256 CU x 8 blocks, grid-stride

__global__ __launch_bounds__(BLOCK) void flow_loss_partial(
    const float* __restrict__ flow,   // (B,H,W,2)
    const float* __restrict__ im1,    // (B,C,H,W)
    const float* __restrict__ im2,    // (B,C,H,W)
    float* __restrict__ partials)     // [GRID]
{
    float acc = 0.0f;

    for (int i = blockIdx.x * BLOCK + threadIdx.x; i < NPIX; i += GRID * BLOCK) {
        const int b   = i >> 19;          // / HW
        const int rem = i & (HW - 1);
        const int y   = rem >> 10;        // / W
        const int x   = rem & (W - 1);

        const float2 f = *reinterpret_cast<const float2*>(flow + 2 * i);

        // Replicate reference arithmetic sequence exactly (f32 ops).
        const float base_x = (float)x / (float)W * 2.0f - 1.0f;
        const float base_y = (float)y / (float)H * 2.0f - 1.0f;
        const float gx = f.x / (float)W + base_x;
        const float gy = f.y / (float)H + base_y;
        const float ix = ((gx + 1.0f) * (float)W - 1.0f) * 0.5f;
        const float iy = ((gy + 1.0f) * (float)H - 1.0f) * 0.5f;

        const float x0f = floorf(ix);
        const float y0f = floorf(iy);
        const float wx1 = ix - x0f, wx0 = 1.0f - wx1;
        const float wy1 = iy - y0f, wy0 = 1.0f - wy1;

        const int x0 = (int)x0f, y0 = (int)y0f;
        const int x1 = x0 + 1,   y1 = y0 + 1;

        const bool vx0 = (x0 >= 0) & (x0 < W);
        const bool vx1 = (x1 >= 0) & (x1 < W);
        const bool vy0 = (y0 >= 0) & (y0 < H);
        const bool vy1 = (y1 >= 0) & (y1 < H);

        const float w00 = wx0 * wy0 * (float)(vx0 & vy0);
        const float w01 = wx1 * wy0 * (float)(vx1 & vy0);
        const float w10 = wx0 * wy1 * (float)(vx0 & vy1);
        const float w11 = wx1 * wy1 * (float)(vx1 & vy1);

        const int x0c = min(max(x0, 0), W - 1);
        const int x1c = min(max(x1, 0), W - 1);
        const int y0c = min(max(y0, 0), H - 1);
        const int y1c = min(max(y1, 0), H - 1);

        const int o00 = y0c * W + x0c;
        const int o01 = y0c * W + x1c;
        const int o10 = y1c * W + x0c;
        const int o11 = y1c * W + x1c;

        const float* p1 = im1 + b * C * HW;
        const float* p2 = im2 + b * C * HW;

#pragma unroll
        for (int c = 0; c < C; ++c) {
            const float* pl = p1 + c * HW;
            const float warp = w00 * pl[o00] + w01 * pl[o01]
                             + w10 * pl[o10] + w11 * pl[o11];
            acc += fabsf(p2[c * HW + rem] - warp);
        }
    }

    // wave64 reduce
    #pragma unroll
    for (int off = 32; off > 0; off >>= 1)
        acc += __shfl_down(acc, off, 64);

    __shared__ float lds[BLOCK / 64];
    const int lane = threadIdx.x & 63;
    const int wid  = threadIdx.x >> 6;
    if (lane == 0) lds[wid] = acc;
    __syncthreads();
    if (threadIdx.x == 0) {
        float s = 0.0f;
        #pragma unroll
        for (int wv = 0; wv < BLOCK / 64; ++wv) s += lds[wv];
        partials[blockIdx.x] = s;
    }
}

__global__ __launch_bounds__(BLOCK) void flow_loss_reduce(
    const float* __restrict__ partials, float* __restrict__ out)
{
    __shared__ double lds[BLOCK];
    double s = 0.0;
    for (int i = threadIdx.x; i < GRID; i += BLOCK) s += (double)partials[i];
    lds[threadIdx.x] = s;
    __syncthreads();
    for (int off = BLOCK / 2; off > 0; off >>= 1) {
        if (threadIdx.x < off) lds[threadIdx.x] += lds[threadIdx.x + off];
        __syncthreads();
    }
    if (threadIdx.x == 0) out[0] = (float)(lds[0] / (double)(W * H));
}

} // namespace

extern "C" void kernel_launch(void* const* d_in, const int* in_sizes, int n_in,
                              void* d_out, int out_size, void* d_ws, size_t ws_size,
                              hipStream_t stream) {
    const float* flow = (const float*)d_in[0];
    const float* im1  = (const float*)d_in[1];
    const float* im2  = (const float*)d_in[2];
    float* out = (float*)d_out;
    float* partials = (float*)d_ws;

    flow_loss_partial<<<GRID, BLOCK, 0, stream>>>(flow, im1, im2, partials);
    flow_loss_reduce<<<1, BLOCK, 0, stream>>>(partials, out);
}